// Round 14
// baseline (225.730 us; speedup 1.0000x reference)
//
#include <hip/hip_runtime.h>
#include <hip/hip_bf16.h>
#include <stdint.h>

// ExpanderLinear: y[t,o] = sum_i x[t,i] * (w[o,i]*mask[o,i]) + bias[o]
// M=8192, K=4096, N=4096. f32 in/out. INT8 MFMA path.
// R14: B (wq) stored FRAGMENT-MAJOR and loaded global->VGPR directly
// (no LDS for B). LDS = A-ring-4 only (64KB). Per K-tile: 8 A ds_reads +
// 4 B global loads (dbuf, 1 tile ahead) + 2 A gload_lds (2 tiles ahead) +
// 32 MFMA, 2 barriers. WVM(2) at tile end. T1+T2(A)+T5 kept.

typedef __attribute__((ext_vector_type(4))) float f32x4;
typedef __attribute__((ext_vector_type(4))) int   i32x4;

static constexpr int M = 8192;
static constexpr int N = 4096;
static constexpr int K = 4096;
static constexpr int NT = K / 64;      // 64 K-tiles

#define GLOBAL_AS(p) ((const __attribute__((address_space(1))) void*)(p))
#define LDS_AS(p)    ((__attribute__((address_space(3))) void*)(p))

// ---- prep 1: per-row quant of x -> i8 (row-major) + sx ----
__global__ void __launch_bounds__(256)
quant_x(const float* __restrict__ x, signed char* __restrict__ xq,
        float* __restrict__ sx) {
    const int row = blockIdx.x, tid = threadIdx.x;
    const f32x4* xr = (const f32x4*)(x + (size_t)row * K);
    f32x4 v[4];
    float am = 0.0f;
#pragma unroll
    for (int c = 0; c < 4; ++c) {
        v[c] = xr[c * 256 + tid];
        am = fmaxf(am, fmaxf(fmaxf(fabsf(v[c].x), fabsf(v[c].y)),
                             fmaxf(fabsf(v[c].z), fabsf(v[c].w))));
    }
#pragma unroll
    for (int off = 32; off; off >>= 1) am = fmaxf(am, __shfl_xor(am, off));
    __shared__ float red[4];
    if ((tid & 63) == 0) red[tid >> 6] = am;
    __syncthreads();
    am = fmaxf(fmaxf(red[0], red[1]), fmaxf(red[2], red[3]));
    const float inv = am > 0.0f ? 127.0f / am : 0.0f;
    int* out = (int*)xq + (size_t)row * (K / 4);
#pragma unroll
    for (int c = 0; c < 4; ++c) {
        int q0 = (int)__builtin_rintf(v[c].x * inv) & 255;
        int q1 = (int)__builtin_rintf(v[c].y * inv) & 255;
        int q2 = (int)__builtin_rintf(v[c].z * inv) & 255;
        int q3 = (int)__builtin_rintf(v[c].w * inv) & 255;
        out[c * 256 + tid] = q0 | (q1 << 8) | (q2 << 16) | (q3 << 24);
    }
    if (tid == 0) sx[row] = am * (1.0f / 127.0f);
}

// ---- prep 2: per-row quant of (w*mask) -> i8 FRAGMENT-MAJOR + sw ----
// Thread tid quantizes floats [tid*16, tid*16+16) of its row into one 16B
// chunk at ((S*64 + kk)*64 + fq*16 + fr)*16, S=row>>4, fr=row&15,
// kk=tid>>2, fq=tid&3  (so GEMM lane (fq,fr) reads k-bytes [kk*64+fq*16).
__global__ void __launch_bounds__(256)
quant_w(const float* __restrict__ w, const int* __restrict__ mask,
        signed char* __restrict__ wqf, float* __restrict__ sw) {
    const int row = blockIdx.x, tid = threadIdx.x;
    const size_t base = (size_t)row * K + (size_t)tid * 16;
    f32x4 v[4];
    float am = 0.0f;
#pragma unroll
    for (int c = 0; c < 4; ++c) {
        f32x4 wv = *(const f32x4*)(w + base + c * 4);
        i32x4 mv = *(const i32x4*)(mask + base + c * 4);
        v[c].x = mv.x ? wv.x : 0.0f;
        v[c].y = mv.y ? wv.y : 0.0f;
        v[c].z = mv.z ? wv.z : 0.0f;
        v[c].w = mv.w ? wv.w : 0.0f;
        am = fmaxf(am, fmaxf(fmaxf(fabsf(v[c].x), fabsf(v[c].y)),
                             fmaxf(fabsf(v[c].z), fabsf(v[c].w))));
    }
#pragma unroll
    for (int off = 32; off; off >>= 1) am = fmaxf(am, __shfl_xor(am, off));
    __shared__ float red[4];
    if ((tid & 63) == 0) red[tid >> 6] = am;
    __syncthreads();
    am = fmaxf(fmaxf(red[0], red[1]), fmaxf(red[2], red[3]));
    const float inv = am > 0.0f ? 127.0f / am : 0.0f;
    i32x4 q;
#pragma unroll
    for (int c = 0; c < 4; ++c) {
        int q0 = (int)__builtin_rintf(v[c].x * inv) & 255;
        int q1 = (int)__builtin_rintf(v[c].y * inv) & 255;
        int q2 = (int)__builtin_rintf(v[c].z * inv) & 255;
        int q3 = (int)__builtin_rintf(v[c].w * inv) & 255;
        q[c] = q0 | (q1 << 8) | (q2 << 16) | (q3 << 24);
    }
    const size_t off16 = ((size_t)(row >> 4) * 64 + (tid >> 2)) * 64
                         + (size_t)(tid & 3) * 16 + (row & 15);
    ((i32x4*)wqf)[off16] = q;
    if (tid == 0) sw[row] = am * (1.0f / 127.0f);
}

// ---- main GEMM (i8, A via LDS ring-4, B fragment-direct) ----
// LDS: A-ring = 4 units of [256 rows][64 B] (16KB each) = 64 KiB.
// Tile t: A in slot t&3 (staged at t-2); B(t) in regs (loaded at t-1).
// Per tile: {BPRE B(t+1); STGA slot(t+2); 8 ds_read A(t); BAR;
//            32 MFMA; WVM(2); BAR}.
// A swizzle within 128B row-pair: phys3 = (((row&1)<<2)|fq) ^ ((row>>1)&7);
// LDS writes linear (global_load_lds); global SOURCE pre-swizzled (s3w).
__global__ void __launch_bounds__(512, 2)
gemmI8(const signed char* __restrict__ A,    // [M][K] i8 row-major
       const signed char* __restrict__ Bf,   // [N/16][64][64][16] frag-major
       const float* __restrict__ sx,         // [M]
       const float* __restrict__ sw,         // [N]
       const float* __restrict__ bias,       // [N]
       float* __restrict__ C) {              // [M][N] f32
    extern __shared__ unsigned char lds[];
    unsigned char* __restrict__ Au = lds;    // 4 * 16384 B

    const int tid  = threadIdx.x;
    const int lane = tid & 63;
    const int wave = tid >> 6;

    // T1: XCD-aware bijective swizzle (nwg = 512, % 8 == 0)
    const int bid = blockIdx.x;
    const int swz = (bid & 7) * 64 + (bid >> 3);
    const int brow = (swz >> 4) * 256;         // ntn = 16
    const int bcol = (swz & 15) * 256;

    const int wrow = (wave >> 2) * 128;        // wave output rows
    const int wcol = (wave & 3) * 64;          // wave output cols
    const int fr = lane & 15;                  // fragment row/col
    const int fq = lane >> 4;                  // k-subgroup (16B each)

    // A read-side swizzle base (byte offset within a 16KB unit)
    const int s3r   = (((fr & 1) << 2) | fq) ^ (fr >> 1);
    const int abase = wrow * 64 + (fr >> 1) * 128 + s3r * 16;   // + m*1024

    // A write-side: lane's linear LDS slot -> logical (row, byte-col)
    const int l8 = lane & 7, lh = lane >> 3;
    const int s3w    = l8 ^ lh;
    const int wrow_l = 2 * lh + (s3w >> 2);
    const int wcol_b = (s3w & 3) * 16;

    const signed char* __restrict__ Ag = A + (size_t)brow * K;
    // B fragment base: column-block SB0 + n, K-tile t, lane*16
    const int SB0 = (bcol + wcol) >> 4;
    const signed char* __restrict__ Bg = Bf + (size_t)SB0 * 65536 + lane * 16;

    i32x4 acc[8][4];
#pragma unroll
    for (int m = 0; m < 8; ++m)
#pragma unroll
        for (int n = 0; n < 4; ++n) acc[m][n] = (i32x4)(0);

    i32x4 afL[4], afH[4], bA[4], bB[4];

#define STG1(dst, src) __builtin_amdgcn_global_load_lds(GLOBAL_AS(src), LDS_AS(dst), 16, 0, 0)
#define STGA(slot, j) do {                                                      \
    _Pragma("unroll")                                                           \
    for (int c = 0; c < 2; ++c) {                                               \
        const int q_ = c * 8 + wave;                                            \
        STG1(Au + (slot) * 16384 + q_ * 1024,                                   \
             Ag + (size_t)(q_ * 16 + wrow_l) * K + (j) * 64 + wcol_b);          \
    }                                                                           \
  } while (0)
#define BPRE(buf, t_) do {                                                      \
    _Pragma("unroll")                                                           \
    for (int n = 0; n < 4; ++n)                                                 \
        buf[n] = *(const i32x4*)(Bg + (size_t)n * 65536 + (t_) * 1024);         \
  } while (0)
#define LDA4(buf, unit, m0) do {                                                \
    const unsigned char* ub_ = Au + (unit) * 16384;                             \
    _Pragma("unroll")                                                           \
    for (int i = 0; i < 4; ++i)                                                 \
        buf[i] = *(const i32x4*)(ub_ + abase + ((m0) + i) * 1024);              \
  } while (0)
#define MM16(a, b, r0) do {                                                     \
    __builtin_amdgcn_s_setprio(1);                                              \
    _Pragma("unroll")                                                           \
    for (int i = 0; i < 4; ++i)                                                 \
      _Pragma("unroll")                                                         \
      for (int n = 0; n < 4; ++n)                                               \
        acc[(r0) + i][n] = __builtin_amdgcn_mfma_i32_16x16x64_i8(               \
            a[i], b[n], acc[(r0) + i][n], 0, 0, 0);                             \
    __builtin_amdgcn_s_setprio(0);                                              \
  } while (0)
#define BAR    __builtin_amdgcn_s_barrier()
#define FENCE  asm volatile("" ::: "memory")
#define WVM2   asm volatile("s_waitcnt vmcnt(2)" ::: "memory")
#define WVM0   asm volatile("s_waitcnt vmcnt(0)" ::: "memory")

    // prologue: stage A tiles 0,1; load B(0) to regs; drain
    STGA(0, 0); STGA(1, 1);
    BPRE(bA, 0);
    WVM0;
    BAR; FENCE;

#pragma unroll 1
    for (int t = 0; t < NT - 2; t += 2) {
        // even tile t: compute with bA, prefetch B(t+1) -> bB
        BPRE(bB, t + 1);
        STGA((t + 2) & 3, t + 2);
        LDA4(afL, t & 3, 0); LDA4(afH, t & 3, 4);
        BAR; FENCE;
        MM16(afL, bA, 0); MM16(afH, bA, 4);
        WVM2;                 // retires B(t+1) + A(t+1) stage batch
        BAR; FENCE;
        // odd tile t+1: compute with bB, prefetch B(t+2) -> bA
        BPRE(bA, t + 2);
        STGA((t + 3) & 3, t + 3);
        LDA4(afL, (t + 1) & 3, 0); LDA4(afH, (t + 1) & 3, 4);
        BAR; FENCE;
        MM16(afL, bB, 0); MM16(afH, bB, 4);
        WVM2;                 // retires B(t+2) + A(t+2) stage batch
        BAR; FENCE;
    }
    {   // tile NT-2 = 62 (slot 2), B in bA; prefetch B(63); no staging
        BPRE(bB, NT - 1);
        LDA4(afL, (NT - 2) & 3, 0); LDA4(afH, (NT - 2) & 3, 4);
        BAR; FENCE;
        MM16(afL, bA, 0); MM16(afH, bA, 4);
        WVM0;                 // drain B(63) + A(63) stage batch
        BAR; FENCE;
        // tile NT-1 = 63 (slot 3), B in bB
        LDA4(afL, (NT - 1) & 3, 0); LDA4(afH, (NT - 1) & 3, 4);
        FENCE;
        MM16(afL, bB, 0); MM16(afH, bB, 4);
    }

    // epilogue: C/D layout col=lane&15, row=(lane>>4)*4+reg (dtype-indep,
    // m121-m128); y = acc * sx[row]*sw[col] + bias[col]
    float swv[4], bvv[4];
#pragma unroll
    for (int n = 0; n < 4; ++n) {
        const int col = bcol + wcol + n * 16 + fr;
        swv[n] = sw[col];
        bvv[n] = bias[col];
    }
#pragma unroll
    for (int m = 0; m < 8; ++m) {
#pragma unroll
        for (int j = 0; j < 4; ++j) {
            const int row = brow + wrow + m * 16 + fq * 4 + j;
            const float sxr = sx[row];
            float* crow = C + (size_t)row * N + bcol + wcol + fr;
#pragma unroll
            for (int n = 0; n < 4; ++n)
                crow[n * 16] = (float)acc[m][n][j] * (sxr * swv[n]) + bvv[n];
        }
    }
#undef STG1
#undef STGA
#undef BPRE
#undef LDA4
#undef MM16
#undef BAR
#undef FENCE
#undef WVM2
#undef WVM0
}

// ---- fallback (only if ws too small): f32 vector GEMM ----
__global__ void fallback_gemm(const float* __restrict__ x,
                              const float* __restrict__ w,
                              const int* __restrict__ mask,
                              const float* __restrict__ bias,
                              float* __restrict__ C) {
    const int tid = threadIdx.x;
    const int tx = tid & 15, ty = tid >> 4;
    const int brow = blockIdx.y * 64, bcol = blockIdx.x * 64;
    __shared__ float As[64][17];
    __shared__ float Ws[64][17];
    float acc[4][4] = {};
    for (int k0 = 0; k0 < K; k0 += 16) {
        __syncthreads();
        for (int i = tid; i < 64 * 16; i += 256) {
            int r = i >> 4, c = i & 15;
            As[r][c] = x[(size_t)(brow + r) * K + k0 + c];
            float wv = w[(size_t)(bcol + r) * K + k0 + c];
            Ws[r][c] = mask[(size_t)(bcol + r) * K + k0 + c] ? wv : 0.0f;
        }
        __syncthreads();
        for (int kk = 0; kk < 16; ++kk) {
            float a[4], b[4];
#pragma unroll
            for (int i = 0; i < 4; ++i) a[i] = As[ty * 4 + i][kk];
#pragma unroll
            for (int i = 0; i < 4; ++i) b[i] = Ws[tx * 4 + i][kk];
#pragma unroll
            for (int i = 0; i < 4; ++i)
#pragma unroll
                for (int j = 0; j < 4; ++j) acc[i][j] += a[i] * b[j];
        }
    }
    for (int i = 0; i < 4; ++i)
        for (int j = 0; j < 4; ++j) {
            int row = brow + ty * 4 + i, col = bcol + tx * 4 + j;
            C[(size_t)row * N + col] = acc[i][j] + bias[col];
        }
}

extern "C" void kernel_launch(void* const* d_in, const int* in_sizes, int n_in,
                              void* d_out, int out_size, void* d_ws, size_t ws_size,
                              hipStream_t stream) {
    const float* x    = (const float*)d_in[0];
    const float* w    = (const float*)d_in[1];
    const float* bias = (const float*)d_in[2];
    const int*   mask = (const int*)d_in[3];
    float* out = (float*)d_out;

    const size_t xq_b = (size_t)M * K;              // 32 MiB
    const size_t wq_b = (size_t)N * K;              // 16 MiB
    const size_t need = xq_b + wq_b + (M + N) * sizeof(float);
    if (ws_size >= need) {
        signed char* xq  = (signed char*)d_ws;
        signed char* wqf = xq + xq_b;
        float* sx = (float*)(wqf + wq_b);
        float* sw = sx + M;
        (void)hipFuncSetAttribute((const void*)gemmI8,
                                  hipFuncAttributeMaxDynamicSharedMemorySize,
                                  65536);
        quant_x<<<M, 256, 0, stream>>>(x, xq, sx);
        quant_w<<<N, 256, 0, stream>>>(w, mask, wqf, sw);
        gemmI8<<<(M / 256) * (N / 256), 512, 65536, stream>>>(
            xq, wqf, sx, sw, bias, out);
    } else {
        dim3 g(N / 64, M / 64);
        fallback_gemm<<<g, 256, 0, stream>>>(x, w, mask, bias, out);
    }
}

// Round 16
// 197.142 us; speedup vs baseline: 1.1450x; 1.1450x over previous
//
#include <hip/hip_runtime.h>
#include <hip/hip_bf16.h>
#include <stdint.h>

// ExpanderLinear: y = x @ (w*mask)^T + bias. M=8192, K=4096, N=4096.
// INT8 MFMA path (per-row symmetric quant, i32 accum, f32 dequant epilogue).
// R16 = R15's cross-phase register pipeline with the cross-wave race FIXED:
// barrier-first phases. Each phase: {[WVM]; BAR; FENCE; reads-for-next-phase
// (+stage); SCHED0; MFMA on prev-phase regs}. Reads of a staged slot are now
// always after (all-waves-WVM -> barrier); vmcnt is per-wave, so R15's
// "WVM4; reads; ...; BAR" order read rows whose staging loads (issued by
// OTHER waves) had not landed. 2 barriers/tile. No s_setprio (m190).

typedef __attribute__((ext_vector_type(4))) float f32x4;
typedef __attribute__((ext_vector_type(4))) int   i32x4;

static constexpr int M = 8192;
static constexpr int N = 4096;
static constexpr int K = 4096;
static constexpr int NT = K / 64;      // 64 K-tiles

#define GLOBAL_AS(p) ((const __attribute__((address_space(1))) void*)(p))
#define LDS_AS(p)    ((__attribute__((address_space(3))) void*)(p))

// ---- prep 1: per-row quant of x -> i8 + sx ----
__global__ void __launch_bounds__(256)
quant_x(const float* __restrict__ x, signed char* __restrict__ xq,
        float* __restrict__ sx) {
    const int row = blockIdx.x, tid = threadIdx.x;
    const f32x4* xr = (const f32x4*)(x + (size_t)row * K);
    f32x4 v[4];
    float am = 0.0f;
#pragma unroll
    for (int c = 0; c < 4; ++c) {
        v[c] = xr[c * 256 + tid];
        am = fmaxf(am, fmaxf(fmaxf(fabsf(v[c].x), fabsf(v[c].y)),
                             fmaxf(fabsf(v[c].z), fabsf(v[c].w))));
    }
#pragma unroll
    for (int off = 32; off; off >>= 1) am = fmaxf(am, __shfl_xor(am, off));
    __shared__ float red[4];
    if ((tid & 63) == 0) red[tid >> 6] = am;
    __syncthreads();
    am = fmaxf(fmaxf(red[0], red[1]), fmaxf(red[2], red[3]));
    const float inv = am > 0.0f ? 127.0f / am : 0.0f;
    int* out = (int*)xq + (size_t)row * (K / 4);
#pragma unroll
    for (int c = 0; c < 4; ++c) {
        int q0 = (int)__builtin_rintf(v[c].x * inv) & 255;
        int q1 = (int)__builtin_rintf(v[c].y * inv) & 255;
        int q2 = (int)__builtin_rintf(v[c].z * inv) & 255;
        int q3 = (int)__builtin_rintf(v[c].w * inv) & 255;
        out[c * 256 + tid] = q0 | (q1 << 8) | (q2 << 16) | (q3 << 24);
    }
    if (tid == 0) sx[row] = am * (1.0f / 127.0f);
}

// ---- prep 2: per-row quant of (w*mask) -> i8 + sw ----
__global__ void __launch_bounds__(256)
quant_w(const float* __restrict__ w, const int* __restrict__ mask,
        signed char* __restrict__ wq, float* __restrict__ sw) {
    const int row = blockIdx.x, tid = threadIdx.x;
    const f32x4* wr = (const f32x4*)(w + (size_t)row * K);
    const i32x4* mr = (const i32x4*)(mask + (size_t)row * K);
    f32x4 v[4];
    float am = 0.0f;
#pragma unroll
    for (int c = 0; c < 4; ++c) {
        f32x4 wv = wr[c * 256 + tid];
        i32x4 mv = mr[c * 256 + tid];
        v[c].x = mv.x ? wv.x : 0.0f;
        v[c].y = mv.y ? wv.y : 0.0f;
        v[c].z = mv.z ? wv.z : 0.0f;
        v[c].w = mv.w ? wv.w : 0.0f;
        am = fmaxf(am, fmaxf(fmaxf(fabsf(v[c].x), fabsf(v[c].y)),
                             fmaxf(fabsf(v[c].z), fabsf(v[c].w))));
    }
#pragma unroll
    for (int off = 32; off; off >>= 1) am = fmaxf(am, __shfl_xor(am, off));
    __shared__ float red[4];
    if ((tid & 63) == 0) red[tid >> 6] = am;
    __syncthreads();
    am = fmaxf(fmaxf(red[0], red[1]), fmaxf(red[2], red[3]));
    const float inv = am > 0.0f ? 127.0f / am : 0.0f;
    int* out = (int*)wq + (size_t)row * (K / 4);
#pragma unroll
    for (int c = 0; c < 4; ++c) {
        int q0 = (int)__builtin_rintf(v[c].x * inv) & 255;
        int q1 = (int)__builtin_rintf(v[c].y * inv) & 255;
        int q2 = (int)__builtin_rintf(v[c].z * inv) & 255;
        int q3 = (int)__builtin_rintf(v[c].w * inv) & 255;
        out[c * 256 + tid] = q0 | (q1 << 8) | (q2 << 16) | (q3 << 24);
    }
    if (tid == 0) sw[row] = am * (1.0f / 127.0f);
}

// ---- main GEMM (i8, barrier-first pipelined phases) ----
// LDS: A-ring = 4 units of [256 rows][64 B] (16KB each), B-ring same (128KB).
// Tile t in slot t&3. PhA(t): {BAR; read A-high(t)->A1; stage S_AB(t+2);
// MM rows0-3 on A0/Bc}. PhB(t): {WVM4; BAR; read A-low(t+1)->A0 +
// B(t+1)->Bn; MM rows4-7 on A1/Bc}. WVM4 retires S_AB(t+1) (oldest 4 of 8);
// barrier after it makes ALL waves' staging of slot t+1 visible pre-read.
// Swizzle within 128B row-pair: phys3 = (((row&1)<<2)|fq) ^ ((row>>1)&7);
// LDS writes linear (global_load_lds); global SOURCE pre-swizzled (s3w).
__global__ void __launch_bounds__(512, 2)
gemmI8(const signed char* __restrict__ A,   // [M][K] i8
       const signed char* __restrict__ B,   // [N][K] i8
       const float* __restrict__ sx,        // [M]
       const float* __restrict__ sw,        // [N]
       const float* __restrict__ bias,      // [N]
       float* __restrict__ C) {             // [M][N] f32
    extern __shared__ unsigned char lds[];
    unsigned char* __restrict__ Au = lds;            // 4 * 16384 B
    unsigned char* __restrict__ Bu = lds + 65536;    // 4 * 16384 B

    const int tid  = threadIdx.x;
    const int lane = tid & 63;
    const int wave = tid >> 6;

    // T1: XCD-aware bijective swizzle (nwg = 512, % 8 == 0)
    const int bid = blockIdx.x;
    const int swz = (bid & 7) * 64 + (bid >> 3);
    const int brow = (swz >> 4) * 256;         // ntn = 16
    const int bcol = (swz & 15) * 256;

    const int wrow = (wave >> 2) * 128;        // wave output rows
    const int wcol = (wave & 3) * 64;          // wave output cols
    const int fr = lane & 15;                  // fragment row/col
    const int fq = lane >> 4;                  // k-subgroup (16B each)

    // read-side swizzle bases (byte offsets within a 16KB unit)
    const int s3r   = (((fr & 1) << 2) | fq) ^ (fr >> 1);
    const int abase = wrow * 64 + (fr >> 1) * 128 + s3r * 16;   // + m*1024
    const int bbase = wcol * 64 + (fr >> 1) * 128 + s3r * 16;   // + n*1024

    // write-side: lane's linear LDS slot -> logical (row, byte-col) in global
    const int l8 = lane & 7, lh = lane >> 3;
    const int s3w    = l8 ^ lh;
    const int wrow_l = 2 * lh + (s3w >> 2);    // row within 16-row chunk
    const int wcol_b = (s3w & 3) * 16;         // byte col within 64-B row

    const signed char* __restrict__ Ag = A + (size_t)brow * K;
    const signed char* __restrict__ Bg = B + (size_t)bcol * K;

    i32x4 acc[8][4];
#pragma unroll
    for (int m = 0; m < 8; ++m)
#pragma unroll
        for (int n = 0; n < 4; ++n) acc[m][n] = (i32x4)(0);

    // pipelined operand registers (static names, rule #20)
    i32x4 A0[4], A1[4], B0[4], B1[4];

#define STG1(dst, src) __builtin_amdgcn_global_load_lds(GLOBAL_AS(src), LDS_AS(dst), 16, 0, 0)
#define SAB(slot, j) do {                                                       \
    _Pragma("unroll")                                                           \
    for (int c = 0; c < 2; ++c) {                                               \
        const int q_ = c * 8 + wave;                                            \
        STG1(Au + (slot) * 16384 + q_ * 1024,                                   \
             Ag + (size_t)(q_ * 16 + wrow_l) * K + (j) * 64 + wcol_b);          \
    }                                                                           \
    _Pragma("unroll")                                                           \
    for (int c = 0; c < 2; ++c) {                                               \
        const int q_ = c * 8 + wave;                                            \
        STG1(Bu + (slot) * 16384 + q_ * 1024,                                   \
             Bg + (size_t)(q_ * 16 + wrow_l) * K + (j) * 64 + wcol_b);          \
    }                                                                           \
  } while (0)
#define LDA4(buf, unit, m0) do {                                                \
    const unsigned char* ub_ = Au + (unit) * 16384;                             \
    _Pragma("unroll")                                                           \
    for (int i = 0; i < 4; ++i)                                                 \
        buf[i] = *(const i32x4*)(ub_ + abase + ((m0) + i) * 1024);              \
  } while (0)
#define LDB4(buf, unit) do {                                                    \
    const unsigned char* vb_ = Bu + (unit) * 16384;                             \
    _Pragma("unroll")                                                           \
    for (int n = 0; n < 4; ++n)                                                 \
        buf[n] = *(const i32x4*)(vb_ + bbase + n * 1024);                       \
  } while (0)
#define MM16(a, b, r0) do {                                                     \
    _Pragma("unroll")                                                           \
    for (int i = 0; i < 4; ++i)                                                 \
      _Pragma("unroll")                                                         \
      for (int n = 0; n < 4; ++n)                                               \
        acc[(r0) + i][n] = __builtin_amdgcn_mfma_i32_16x16x64_i8(               \
            a[i], b[n], acc[(r0) + i][n], 0, 0, 0);                             \
  } while (0)
#define BAR    __builtin_amdgcn_s_barrier()
#define FENCE  asm volatile("" ::: "memory")
#define SCHED0 __builtin_amdgcn_sched_barrier(0)
#define WVM4   asm volatile("s_waitcnt vmcnt(4)" ::: "memory")
#define WVM0   asm volatile("s_waitcnt vmcnt(0)" ::: "memory")

// PhA(t): BAR; read A-high(t) for PhB; stage t+2; MM rows0-3 (prev regs)
#define PHA(ut, s2, j2, bc) do {                                                \
    BAR; FENCE;                                                                 \
    LDA4(A1, ut, 4);                                                            \
    SAB(s2, j2);                                                                \
    SCHED0;                                                                     \
    MM16(A0, bc, 0);                                                            \
  } while (0)
#define PHA_NOST(ut, bc) do {                                                   \
    BAR; FENCE;                                                                 \
    LDA4(A1, ut, 4);                                                            \
    SCHED0;                                                                     \
    MM16(A0, bc, 0);                                                            \
  } while (0)
// PhB(t): WVM+BAR makes slot t+1 staging visible; read its A-low + B;
// MM rows4-7 (A1 read in PhA).
#define PHB(un, bn, bc) do {                                                    \
    WVM4; BAR; FENCE;                                                           \
    LDA4(A0, un, 0);                                                            \
    LDB4(bn, un);                                                               \
    SCHED0;                                                                     \
    MM16(A1, bc, 4);                                                            \
  } while (0)
#define PHB0(un, bn, bc) do {                                                   \
    WVM0; BAR; FENCE;                                                           \
    LDA4(A0, un, 0);                                                            \
    LDB4(bn, un);                                                               \
    SCHED0;                                                                     \
    MM16(A1, bc, 4);                                                            \
  } while (0)

    // prologue: stage tiles 0,1; retire tile 0 (all waves) via WVM4+BAR;
    // preload tile0 A-low + B.
    SAB(0, 0); SAB(1, 1);
    WVM4;                  // 8 outstanding -> 4: S_AB(0) retired
    BAR; FENCE;
    LDA4(A0, 0, 0); LDB4(B0, 0);

#pragma unroll 1
    for (int t = 0; t < NT - 4; t += 2) {
        const int u0 = t & 3, u1 = (t + 1) & 3;
        const int s2 = (t + 2) & 3, s3 = (t + 3) & 3;
        // even tile t: Bc=B0, Bn=B1
        PHA(u0, s2, t + 2, B0);
        PHB(u1, B1, B0);
        // odd tile t+1: Bc=B1, Bn=B0
        PHA(u1, s3, t + 3, B1);
        PHB(s2, B0, B1);            // next-tile slot (t+2)&3 == s2
    }
    // peeled tiles 60..63 (slots 0,1,2,3); stages S_AB(62), S_AB(63) here
    PHA(0, 2, 62, B0);              // tile 60 PhA
    PHB(1, B1, B0);                 // tile 60 PhB (WVM4 retires S_AB(61))
    PHA(1, 3, 63, B1);              // tile 61 PhA
    PHB(2, B0, B1);                 // tile 61 PhB (WVM4 retires S_AB(62))
    PHA_NOST(2, B0);                // tile 62 PhA
    PHB0(3, B1, B0);                // tile 62 PhB (WVM0 retires S_AB(63))
    PHA_NOST(3, B1);                // tile 63 PhA
    FENCE;
    MM16(A1, B1, 4);                // tile 63 PhB (no reads, no barrier)

    // epilogue: C/D layout col=lane&15, row=(lane>>4)*4+reg (dtype-indep,
    // m121-m128); y = acc * sx[row]*sw[col] + bias[col]
    float swv[4], bvv[4];
#pragma unroll
    for (int n = 0; n < 4; ++n) {
        const int col = bcol + wcol + n * 16 + fr;
        swv[n] = sw[col];
        bvv[n] = bias[col];
    }
#pragma unroll
    for (int m = 0; m < 8; ++m) {
#pragma unroll
        for (int j = 0; j < 4; ++j) {
            const int row = brow + wrow + m * 16 + fq * 4 + j;
            const float sxr = sx[row];
            float* crow = C + (size_t)row * N + bcol + wcol + fr;
#pragma unroll
            for (int n = 0; n < 4; ++n)
                crow[n * 16] = (float)acc[m][n][j] * (sxr * swv[n]) + bvv[n];
        }
    }
#undef STG1
#undef SAB
#undef LDA4
#undef LDB4
#undef MM16
#undef BAR
#undef FENCE
#undef SCHED0
#undef WVM4
#undef WVM0
#undef PHA
#undef PHA_NOST
#undef PHB
#undef PHB0
}

// ---- fallback (only if ws too small): f32 vector GEMM ----
__global__ void fallback_gemm(const float* __restrict__ x,
                              const float* __restrict__ w,
                              const int* __restrict__ mask,
                              const float* __restrict__ bias,
                              float* __restrict__ C) {
    const int tid = threadIdx.x;
    const int tx = tid & 15, ty = tid >> 4;
    const int brow = blockIdx.y * 64, bcol = blockIdx.x * 64;
    __shared__ float As[64][17];
    __shared__ float Ws[64][17];
    float acc[4][4] = {};
    for (int k0 = 0; k0 < K; k0 += 16) {
        __syncthreads();
        for (int i = tid; i < 64 * 16; i += 256) {
            int r = i >> 4, c = i & 15;
            As[r][c] = x[(size_t)(brow + r) * K + k0 + c];
            float wv = w[(size_t)(bcol + r) * K + k0 + c];
            Ws[r][c] = mask[(size_t)(bcol + r) * K + k0 + c] ? wv : 0.0f;
        }
        __syncthreads();
        for (int kk = 0; kk < 16; ++kk) {
            float a[4], b[4];
#pragma unroll
            for (int i = 0; i < 4; ++i) a[i] = As[ty * 4 + i][kk];
#pragma unroll
            for (int i = 0; i < 4; ++i) b[i] = Ws[tx * 4 + i][kk];
#pragma unroll
            for (int i = 0; i < 4; ++i)
#pragma unroll
                for (int j = 0; j < 4; ++j) acc[i][j] += a[i] * b[j];
        }
    }
    for (int i = 0; i < 4; ++i)
        for (int j = 0; j < 4; ++j) {
            int row = brow + ty * 4 + i, col = bcol + tx * 4 + j;
            C[(size_t)row * N + col] = acc[i][j] + bias[col];
        }
}

extern "C" void kernel_launch(void* const* d_in, const int* in_sizes, int n_in,
                              void* d_out, int out_size, void* d_ws, size_t ws_size,
                              hipStream_t stream) {
    const float* x    = (const float*)d_in[0];
    const float* w    = (const float*)d_in[1];
    const float* bias = (const float*)d_in[2];
    const int*   mask = (const int*)d_in[3];
    float* out = (float*)d_out;

    const size_t xq_b = (size_t)M * K;              // 32 MiB
    const size_t wq_b = (size_t)N * K;              // 16 MiB
    const size_t need = xq_b + wq_b + (M + N) * sizeof(float);
    if (ws_size >= need) {
        signed char* xq = (signed char*)d_ws;
        signed char* wq = xq + xq_b;
        float* sx = (float*)(wq + wq_b);
        float* sw = sx + M;
        (void)hipFuncSetAttribute((const void*)gemmI8,
                                  hipFuncAttributeMaxDynamicSharedMemorySize,
                                  131072);
        quant_x<<<M, 256, 0, stream>>>(x, xq, sx);
        quant_w<<<N, 256, 0, stream>>>(w, mask, wq, sw);
        gemmI8<<<(M / 256) * (N / 256), 512, 131072, stream>>>(
            xq, wq, sx, sw, bias, out);
    } else {
        dim3 g(N / 64, M / 64);
        fallback_gemm<<<g, 256, 0, stream>>>(x, w, mask, bias, out);
    }
}

// Round 17
// 196.219 us; speedup vs baseline: 1.1504x; 1.0047x over previous
//
#include <hip/hip_runtime.h>
#include <hip/hip_bf16.h>
#include <stdint.h>

// ExpanderLinear: y = x @ (w*mask)^T + bias. M=8192, K=4096, N=4096.
// INT8 MFMA path (per-row symmetric quant, i32 accum, f32 dequant epilogue).
// R17 = R11 GEMM (best measured: 151-153us, setprio 2-phase) + FUSED prep
// (quant_x and quant_w in one launch, grid M+N, wave-uniform branch) to
// remove the serial launch gap. GEMM structure ceiling documented across 7
// schedule variants (R2..R16: all 38-49% MfmaUtil); LDS-BW-bound.

typedef __attribute__((ext_vector_type(4))) float f32x4;
typedef __attribute__((ext_vector_type(4))) int   i32x4;

static constexpr int M = 8192;
static constexpr int N = 4096;
static constexpr int K = 4096;
static constexpr int NT = K / 64;      // 64 K-tiles

#define GLOBAL_AS(p) ((const __attribute__((address_space(1))) void*)(p))
#define LDS_AS(p)    ((__attribute__((address_space(3))) void*)(p))

// ---- fused prep: rows [0,M) quantize x; rows [M,M+N) quantize w*mask ----
__global__ void __launch_bounds__(256)
quant_fused(const float* __restrict__ x, const float* __restrict__ w,
            const int* __restrict__ mask,
            signed char* __restrict__ xq, signed char* __restrict__ wq,
            float* __restrict__ sx, float* __restrict__ sw) {
    const int row = blockIdx.x, tid = threadIdx.x;
    __shared__ float red[4];
    f32x4 v[4];
    float am = 0.0f;
    if (row < M) {
        const f32x4* xr = (const f32x4*)(x + (size_t)row * K);
#pragma unroll
        for (int c = 0; c < 4; ++c) {
            v[c] = xr[c * 256 + tid];
            am = fmaxf(am, fmaxf(fmaxf(fabsf(v[c].x), fabsf(v[c].y)),
                                 fmaxf(fabsf(v[c].z), fabsf(v[c].w))));
        }
    } else {
        const int rw = row - M;
        const f32x4* wr = (const f32x4*)(w + (size_t)rw * K);
        const i32x4* mr = (const i32x4*)(mask + (size_t)rw * K);
#pragma unroll
        for (int c = 0; c < 4; ++c) {
            f32x4 wv = wr[c * 256 + tid];
            i32x4 mv = mr[c * 256 + tid];
            v[c].x = mv.x ? wv.x : 0.0f;
            v[c].y = mv.y ? wv.y : 0.0f;
            v[c].z = mv.z ? wv.z : 0.0f;
            v[c].w = mv.w ? wv.w : 0.0f;
            am = fmaxf(am, fmaxf(fmaxf(fabsf(v[c].x), fabsf(v[c].y)),
                                 fmaxf(fabsf(v[c].z), fabsf(v[c].w))));
        }
    }
#pragma unroll
    for (int off = 32; off; off >>= 1) am = fmaxf(am, __shfl_xor(am, off));
    if ((tid & 63) == 0) red[tid >> 6] = am;
    __syncthreads();
    am = fmaxf(fmaxf(red[0], red[1]), fmaxf(red[2], red[3]));
    const float inv = am > 0.0f ? 127.0f / am : 0.0f;
    int* out = (row < M) ? ((int*)xq + (size_t)row * (K / 4))
                         : ((int*)wq + (size_t)(row - M) * (K / 4));
#pragma unroll
    for (int c = 0; c < 4; ++c) {
        int q0 = (int)__builtin_rintf(v[c].x * inv) & 255;
        int q1 = (int)__builtin_rintf(v[c].y * inv) & 255;
        int q2 = (int)__builtin_rintf(v[c].z * inv) & 255;
        int q3 = (int)__builtin_rintf(v[c].w * inv) & 255;
        out[c * 256 + tid] = q0 | (q1 << 8) | (q2 << 16) | (q3 << 24);
    }
    if (tid == 0) {
        if (row < M) sx[row] = am * (1.0f / 127.0f);
        else         sw[row - M] = am * (1.0f / 127.0f);
    }
}

// ---- main GEMM (i8) — R11 verbatim (best measured: 151-153us) ----
// LDS: A-ring = 4 units of [256 rows][64 B] (16KB each), B-ring same.
// Unit t (k bytes [64t,64t+64)) in slot t&3. Per K-tile: 2 phases:
//  P1 {LDA m0-3 + LDB n0-3 (8 ds_read_b128), stage A(t+2) 2 gloads,
//      BAR, MM16(m0-3), BAR}
//  P2 {LDA m4-7, stage B(t+2) 2 gloads, BAR, MM16(m4-7), WVM(4), BAR}
// Swizzle within 128B row-pair: phys3 = (((row&1)<<2)|fq) ^ ((row>>1)&7);
// LDS writes linear (global_load_lds); global SOURCE pre-swizzled (s3w).
__global__ void __launch_bounds__(512, 2)
gemmI8(const signed char* __restrict__ A,   // [M][K] i8
       const signed char* __restrict__ B,   // [N][K] i8
       const float* __restrict__ sx,        // [M]
       const float* __restrict__ sw,        // [N]
       const float* __restrict__ bias,      // [N]
       float* __restrict__ C) {             // [M][N] f32
    extern __shared__ unsigned char lds[];
    unsigned char* __restrict__ Au = lds;            // 4 * 16384 B
    unsigned char* __restrict__ Bu = lds + 65536;    // 4 * 16384 B

    const int tid  = threadIdx.x;
    const int lane = tid & 63;
    const int wave = tid >> 6;

    // T1: XCD-aware bijective swizzle (nwg = 512, % 8 == 0)
    const int bid = blockIdx.x;
    const int swz = (bid & 7) * 64 + (bid >> 3);
    const int brow = (swz >> 4) * 256;         // ntn = 16
    const int bcol = (swz & 15) * 256;

    const int wrow = (wave >> 2) * 128;        // wave output rows
    const int wcol = (wave & 3) * 64;          // wave output cols
    const int fr = lane & 15;                  // fragment row/col
    const int fq = lane >> 4;                  // k-subgroup (16B each)

    // read-side swizzle bases (byte offsets within a 16KB unit)
    const int s3r   = (((fr & 1) << 2) | fq) ^ (fr >> 1);
    const int abase = wrow * 64 + (fr >> 1) * 128 + s3r * 16;   // + m*1024
    const int bbase = wcol * 64 + (fr >> 1) * 128 + s3r * 16;   // + n*1024

    // write-side: lane's linear LDS slot -> logical (row, byte-col) in global
    const int l8 = lane & 7, lh = lane >> 3;
    const int s3w    = l8 ^ lh;
    const int wrow_l = 2 * lh + (s3w >> 2);    // row within 16-row chunk
    const int wcol_b = (s3w & 3) * 16;         // byte col within 64-B row

    const signed char* __restrict__ Ag = A + (size_t)brow * K;
    const signed char* __restrict__ Bg = B + (size_t)bcol * K;

    i32x4 acc[8][4];
#pragma unroll
    for (int m = 0; m < 8; ++m)
#pragma unroll
        for (int n = 0; n < 4; ++n) acc[m][n] = (i32x4)(0);

    i32x4 afL[4], afH[4], bfv[4];

#define STG1(dst, src) __builtin_amdgcn_global_load_lds(GLOBAL_AS(src), LDS_AS(dst), 16, 0, 0)
#define STGA(slot, j) do {                                                      \
    _Pragma("unroll")                                                           \
    for (int c = 0; c < 2; ++c) {                                               \
        const int q_ = c * 8 + wave;                                            \
        STG1(Au + (slot) * 16384 + q_ * 1024,                                   \
             Ag + (size_t)(q_ * 16 + wrow_l) * K + (j) * 64 + wcol_b);          \
    }                                                                           \
  } while (0)
#define STGB(slot, j) do {                                                      \
    _Pragma("unroll")                                                           \
    for (int c = 0; c < 2; ++c) {                                               \
        const int q_ = c * 8 + wave;                                            \
        STG1(Bu + (slot) * 16384 + q_ * 1024,                                   \
             Bg + (size_t)(q_ * 16 + wrow_l) * K + (j) * 64 + wcol_b);          \
    }                                                                           \
  } while (0)
#define LDA4(buf, unit, m0) do {                                                \
    const unsigned char* ub_ = Au + (unit) * 16384;                             \
    _Pragma("unroll")                                                           \
    for (int i = 0; i < 4; ++i)                                                 \
        buf[i] = *(const i32x4*)(ub_ + abase + ((m0) + i) * 1024);              \
  } while (0)
#define LDB4(buf, unit) do {                                                    \
    const unsigned char* vb_ = Bu + (unit) * 16384;                             \
    _Pragma("unroll")                                                           \
    for (int n = 0; n < 4; ++n)                                                 \
        buf[n] = *(const i32x4*)(vb_ + bbase + n * 1024);                       \
  } while (0)
#define MM16(a, r0) do {                                                        \
    __builtin_amdgcn_s_setprio(1);                                              \
    _Pragma("unroll")                                                           \
    for (int i = 0; i < 4; ++i)                                                 \
      _Pragma("unroll")                                                         \
      for (int n = 0; n < 4; ++n)                                               \
        acc[(r0) + i][n] = __builtin_amdgcn_mfma_i32_16x16x64_i8(               \
            a[i], bfv[n], acc[(r0) + i][n], 0, 0, 0);                           \
    __builtin_amdgcn_s_setprio(0);                                              \
  } while (0)
#define BAR    __builtin_amdgcn_s_barrier()
#define FENCE  asm volatile("" ::: "memory")
#define WVM4   asm volatile("s_waitcnt vmcnt(4)" ::: "memory")
#define WVM0   asm volatile("s_waitcnt vmcnt(0)" ::: "memory")

    // prologue: stage tiles 0,1 (A+B each); retire tile 0 (8 -> 4 outstanding)
    STGA(0, 0); STGB(0, 0);
    STGA(1, 1); STGB(1, 1);
    WVM4;
    BAR; FENCE;

#pragma unroll 1
    for (int t = 0; t < NT - 2; ++t) {
        const int u  = t & 3;
        const int s2 = (t + 2) & 3;
        // P1
        LDA4(afL, u, 0); LDB4(bfv, u);
        STGA(s2, t + 2);
        BAR; FENCE;
        MM16(afL, 0);
        BAR; FENCE;
        // P2
        LDA4(afH, u, 4);
        STGB(s2, t + 2);
        BAR; FENCE;
        MM16(afH, 4);
        WVM4;                 // retires tile t+1's 4-gload batch
        BAR; FENCE;
    }
    {   // tile NT-2: no staging; drain tile NT-1's batch at end
        const int u = (NT - 2) & 3;
        LDA4(afL, u, 0); LDB4(bfv, u);
        BAR; FENCE;
        MM16(afL, 0);
        BAR; FENCE;
        LDA4(afH, u, 4);
        BAR; FENCE;
        MM16(afH, 4);
        WVM0;
        BAR; FENCE;
    }
    {   // tile NT-1: no staging, no waits after
        const int u = (NT - 1) & 3;
        LDA4(afL, u, 0); LDB4(bfv, u);
        BAR; FENCE;
        MM16(afL, 0);
        BAR; FENCE;
        LDA4(afH, u, 4);
        FENCE;
        MM16(afH, 4);
    }

    // epilogue: C/D layout col=lane&15, row=(lane>>4)*4+reg (dtype-indep,
    // m121-m128); y = acc * sx[row]*sw[col] + bias[col]
    float swv[4], bvv[4];
#pragma unroll
    for (int n = 0; n < 4; ++n) {
        const int col = bcol + wcol + n * 16 + fr;
        swv[n] = sw[col];
        bvv[n] = bias[col];
    }
#pragma unroll
    for (int m = 0; m < 8; ++m) {
#pragma unroll
        for (int j = 0; j < 4; ++j) {
            const int row = brow + wrow + m * 16 + fq * 4 + j;
            const float sxr = sx[row];
            float* crow = C + (size_t)row * N + bcol + wcol + fr;
#pragma unroll
            for (int n = 0; n < 4; ++n)
                crow[n * 16] = (float)acc[m][n][j] * (sxr * swv[n]) + bvv[n];
        }
    }
#undef STG1
#undef STGA
#undef STGB
#undef LDA4
#undef LDB4
#undef MM16
#undef BAR
#undef FENCE
#undef WVM4
#undef WVM0
}

// ---- fallback (only if ws too small): f32 vector GEMM ----
__global__ void fallback_gemm(const float* __restrict__ x,
                              const float* __restrict__ w,
                              const int* __restrict__ mask,
                              const float* __restrict__ bias,
                              float* __restrict__ C) {
    const int tid = threadIdx.x;
    const int tx = tid & 15, ty = tid >> 4;
    const int brow = blockIdx.y * 64, bcol = blockIdx.x * 64;
    __shared__ float As[64][17];
    __shared__ float Ws[64][17];
    float acc[4][4] = {};
    for (int k0 = 0; k0 < K; k0 += 16) {
        __syncthreads();
        for (int i = tid; i < 64 * 16; i += 256) {
            int r = i >> 4, c = i & 15;
            As[r][c] = x[(size_t)(brow + r) * K + k0 + c];
            float wv = w[(size_t)(bcol + r) * K + k0 + c];
            Ws[r][c] = mask[(size_t)(bcol + r) * K + k0 + c] ? wv : 0.0f;
        }
        __syncthreads();
        for (int kk = 0; kk < 16; ++kk) {
            float a[4], b[4];
#pragma unroll
            for (int i = 0; i < 4; ++i) a[i] = As[ty * 4 + i][kk];
#pragma unroll
            for (int i = 0; i < 4; ++i) b[i] = Ws[tx * 4 + i][kk];
#pragma unroll
            for (int i = 0; i < 4; ++i)
#pragma unroll
                for (int j = 0; j < 4; ++j) acc[i][j] += a[i] * b[j];
        }
    }
    for (int i = 0; i < 4; ++i)
        for (int j = 0; j < 4; ++j) {
            int row = brow + ty * 4 + i, col = bcol + tx * 4 + j;
            C[(size_t)row * N + col] = acc[i][j] + bias[col];
        }
}

extern "C" void kernel_launch(void* const* d_in, const int* in_sizes, int n_in,
                              void* d_out, int out_size, void* d_ws, size_t ws_size,
                              hipStream_t stream) {
    const float* x    = (const float*)d_in[0];
    const float* w    = (const float*)d_in[1];
    const float* bias = (const float*)d_in[2];
    const int*   mask = (const int*)d_in[3];
    float* out = (float*)d_out;

    const size_t xq_b = (size_t)M * K;              // 32 MiB
    const size_t wq_b = (size_t)N * K;              // 16 MiB
    const size_t need = xq_b + wq_b + (M + N) * sizeof(float);
    if (ws_size >= need) {
        signed char* xq = (signed char*)d_ws;
        signed char* wq = xq + xq_b;
        float* sx = (float*)(wq + wq_b);
        float* sw = sx + M;
        (void)hipFuncSetAttribute((const void*)gemmI8,
                                  hipFuncAttributeMaxDynamicSharedMemorySize,
                                  131072);
        quant_fused<<<M + N, 256, 0, stream>>>(x, w, mask, xq, wq, sx, sw);
        gemmI8<<<(M / 256) * (N / 256), 512, 131072, stream>>>(
            xq, wq, sx, sw, bias, out);
    } else {
        dim3 g(N / 64, M / 64);
        fallback_gemm<<<g, 256, 0, stream>>>(x, w, mask, bias, out);
    }
}